// Round 3
// baseline (4419.434 us; speedup 1.0000x reference)
//
#include <hip/hip_runtime.h>
#include <hip/hip_bf16.h>

// Problem constants (from reference)
#define N_NODES 50000
#define N_EDGES 800000
#define R 8
#define NB 30
#define C1 128
#define C2 256
#define C3 512
#define BN_EPS 1e-5f
#define ALPHA 0.01f

static inline unsigned cdivu(long long a, long long b) { return (unsigned)((a + b - 1) / b); }

// ---- basis combine: Wall[r] = sum_b comp[r,b] * basis[b]  ([R, CIN, COUT]) ----
template<int CIN, int COUT>
__global__ void k_wall(const float* __restrict__ comp, const float* __restrict__ basis,
                       float* __restrict__ W) {
    int t = blockIdx.x * blockDim.x + threadIdx.x;
    if (t >= R * CIN * COUT) return;
    int r = t / (CIN * COUT);
    int io = t % (CIN * COUT);          // = i*COUT + o, same layout as basis[b]
    float acc = 0.f;
    for (int b = 0; b < NB; ++b)
        acc += comp[r * NB + b] * basis[(size_t)b * CIN * COUT + io];
    W[t] = acc;
}

// ---- degree per (tgt, rel) ----
__global__ void k_deg(const int* __restrict__ tgt, const int* __restrict__ ety,
                      float* __restrict__ deg) {
    int e = blockIdx.x * blockDim.x + threadIdx.x;
    if (e >= N_EDGES) return;
    atomicAdd(&deg[tgt[e] * R + ety[e]], 1.0f);
}

__global__ void k_inv(float* __restrict__ deg) {
    int t = blockIdx.x * blockDim.x + threadIdx.x;
    if (t < N_NODES * R) deg[t] = 1.0f / fmaxf(deg[t], 1.0f);
}

// ---- per-relation scatter: Xr[tgt] += x[src] * inv[tgt*R+rel]  (wave per edge) ----
template<int CIN>
__global__ void k_scatter_rel(const int* __restrict__ src, const int* __restrict__ tgt,
                              const int* __restrict__ ety, const float* __restrict__ inv,
                              const float* __restrict__ x, float* __restrict__ Xr, int rel) {
    int e = blockIdx.x * 4 + (threadIdx.x >> 6);
    if (e >= N_EDGES) return;
    if (ety[e] != rel) return;          // wave-uniform exit
    int lane = threadIdx.x & 63;
    int s = src[e], t = tgt[e];
    float w = inv[t * R + rel];
    #pragma unroll
    for (int i = lane; i < CIN; i += 64)
        atomicAdd(&Xr[(size_t)t * CIN + i], x[(size_t)s * CIN + i] * w);
}

// ---- tiled fp32 GEMM: C[M,CN] (+)= A[M,K] @ B[K,CN] (+ bias) ----
template<int K, int CN, bool ACC, bool BIAS>
__global__ __launch_bounds__(256) void k_gemm(const float* __restrict__ A,
                                              const float* __restrict__ Bm,
                                              const float* __restrict__ bias,
                                              float* __restrict__ C, int M) {
    __shared__ float As[16][65];
    __shared__ float Bs[16][64];
    int tid = threadIdx.x;
    int tx = tid & 15, ty = tid >> 4;
    int row0 = blockIdx.x * 64;
    int col0 = blockIdx.y * 64;
    float acc[4][4] = {};
    for (int kt = 0; kt < K; kt += 16) {
        {   // A tile: 64 rows x 16 k; each thread loads 4 contiguous k
            int l = tid * 4;
            int m = l >> 4;        // 0..63
            int k = l & 15;        // 0,4,8,12
            int row = row0 + m;
            if (row < M) {
                const float* p = &A[(size_t)row * K + kt + k];
                As[k + 0][m] = p[0]; As[k + 1][m] = p[1];
                As[k + 2][m] = p[2]; As[k + 3][m] = p[3];
            } else {
                As[k + 0][m] = 0.f; As[k + 1][m] = 0.f;
                As[k + 2][m] = 0.f; As[k + 3][m] = 0.f;
            }
        }
        {   // B tile: 16 k x 64 cols
            int l = tid * 4;
            int k = l >> 6;        // 0..15
            int c = l & 63;
            const float* p = &Bm[(size_t)(kt + k) * CN + col0 + c];
            Bs[k][c + 0] = p[0]; Bs[k][c + 1] = p[1];
            Bs[k][c + 2] = p[2]; Bs[k][c + 3] = p[3];
        }
        __syncthreads();
        #pragma unroll
        for (int k = 0; k < 16; ++k) {
            float a[4], b[4];
            #pragma unroll
            for (int i = 0; i < 4; ++i) a[i] = As[k][ty * 4 + i];
            #pragma unroll
            for (int j = 0; j < 4; ++j) b[j] = Bs[k][tx * 4 + j];
            #pragma unroll
            for (int i = 0; i < 4; ++i)
                #pragma unroll
                for (int j = 0; j < 4; ++j)
                    acc[i][j] += a[i] * b[j];
        }
        __syncthreads();
    }
    #pragma unroll
    for (int i = 0; i < 4; ++i) {
        int row = row0 + ty * 4 + i;
        if (row < M) {
            #pragma unroll
            for (int j = 0; j < 4; ++j) {
                int col = col0 + tx * 4 + j;
                float v = acc[i][j];
                if (BIAS) v += bias[col];
                size_t idx = (size_t)row * CN + col;
                if (ACC) v += C[idx];
                C[idx] = v;
            }
        }
    }
}

// ---- per-column sum / sumsq ----
template<int C>
__global__ void k_colstats(const float* __restrict__ h, float* __restrict__ sum,
                           float* __restrict__ ss) {
    int c = threadIdx.x;
    float s = 0.f, q = 0.f;
    for (int r = blockIdx.x; r < N_NODES; r += gridDim.x) {
        float v = h[(size_t)r * C + c];
        s += v; q += v * v;
    }
    atomicAdd(&sum[c], s);
    atomicAdd(&ss[c], q);
}

// ---- BatchNorm (training stats, biased var) + LeakyReLU, in place ----
template<int C>
__global__ void k_bn(float* __restrict__ h, const float* __restrict__ sum,
                     const float* __restrict__ ss, const float* __restrict__ gamma,
                     const float* __restrict__ beta) {
    long long t = (long long)blockIdx.x * blockDim.x + threadIdx.x;
    if (t >= (long long)N_NODES * C) return;
    int c = (int)(t & (C - 1));
    const float invN = 1.0f / (float)N_NODES;
    float mu = sum[c] * invN;
    float var = ss[c] * invN - mu * mu;
    float y = (h[t] - mu) * rsqrtf(fmaxf(var, 0.f) + BN_EPS) * gamma[c] + beta[c];
    h[t] = y > 0.f ? y : ALPHA * y;
}

extern "C" void kernel_launch(void* const* d_in, const int* in_sizes, int n_in,
                              void* d_out, int out_size, void* d_ws, size_t ws_size,
                              hipStream_t stream) {
    const float* x      = (const float*)d_in[0];
    const int*   ei     = (const int*)d_in[1];
    const int*   ety    = (const int*)d_in[2];
    const float* basis1 = (const float*)d_in[3];
    const float* comp1  = (const float*)d_in[4];
    const float* root1  = (const float*)d_in[5];
    const float* bias1  = (const float*)d_in[6];
    const float* gamma1 = (const float*)d_in[7];
    const float* beta1  = (const float*)d_in[8];
    const float* basis2 = (const float*)d_in[9];
    const float* comp2  = (const float*)d_in[10];
    const float* root2  = (const float*)d_in[11];
    const float* bias2  = (const float*)d_in[12];
    const float* gamma2 = (const float*)d_in[13];
    const float* beta2  = (const float*)d_in[14];
    const float* Wf     = (const float*)d_in[15];
    const float* bf_    = (const float*)d_in[16];
    const int* src = ei;
    const int* tgt = ei + N_EDGES;

    // ---- workspace layout (floats), ~212 MB total ----
    float* ws = (float*)d_ws;
    float* h2    = ws;                                  // N*C3      = 25.6M
    float* h1    = h2    + (size_t)N_NODES * C3;        // N*C2      = 12.8M
    float* Xr    = h1    + (size_t)N_NODES * C2;        // N*C2      = 12.8M (reused)
    float* deg   = Xr    + (size_t)N_NODES * C2;        // N*R       = 0.4M
    float* W1all = deg   + (size_t)N_NODES * R;         // R*C1*C2   = 262144
    float* W2all = W1all + (size_t)R * C1 * C2;         // R*C2*C3   = 1048576
    float* stats = W2all + (size_t)R * C2 * C3;         // 1536
    float* sum1 = stats, *ss1 = stats + 256, *sum2 = stats + 512, *ss2 = stats + 1024;

    // zero accumulators (ws is poisoned 0xAA before every launch)
    hipMemsetAsync(deg, 0, (size_t)N_NODES * R * 4, stream);
    hipMemsetAsync(stats, 0, 1536 * 4, stream);

    // weight prep + degrees
    k_wall<C1, C2><<<cdivu((long long)R * C1 * C2, 256), 256, 0, stream>>>(comp1, basis1, W1all);
    k_wall<C2, C3><<<cdivu((long long)R * C2 * C3, 256), 256, 0, stream>>>(comp2, basis2, W2all);
    k_deg<<<cdivu(N_EDGES, 256), 256, 0, stream>>>(tgt, ety, deg);
    k_inv<<<cdivu(N_NODES * R, 256), 256, 0, stream>>>(deg);

    const unsigned scat_grid = cdivu(N_EDGES, 4);   // wave per edge

    // ---- layer 1: h1 = x@root1 + bias1 + sum_r Xr@W1[r] ----
    {
        dim3 g(cdivu(N_NODES, 64), C2 / 64);
        k_gemm<C1, C2, false, true><<<g, 256, 0, stream>>>(x, root1, bias1, h1, N_NODES);
        for (int r = 0; r < R; ++r) {
            hipMemsetAsync(Xr, 0, (size_t)N_NODES * C1 * 4, stream);
            k_scatter_rel<C1><<<scat_grid, 256, 0, stream>>>(src, tgt, ety, deg, x, Xr, r);
            k_gemm<C1, C2, true, false><<<g, 256, 0, stream>>>(
                Xr, W1all + (size_t)r * C1 * C2, nullptr, h1, N_NODES);
        }
    }
    k_colstats<C2><<<512, C2, 0, stream>>>(h1, sum1, ss1);
    k_bn<C2><<<cdivu((long long)N_NODES * C2, 256), 256, 0, stream>>>(h1, sum1, ss1, gamma1, beta1);

    // ---- layer 2: h2 = h1@root2 + bias2 + sum_r Xr@W2[r] ----
    {
        dim3 g(cdivu(N_NODES, 64), C3 / 64);
        k_gemm<C2, C3, false, true><<<g, 256, 0, stream>>>(h1, root2, bias2, h2, N_NODES);
        for (int r = 0; r < R; ++r) {
            hipMemsetAsync(Xr, 0, (size_t)N_NODES * C2 * 4, stream);
            k_scatter_rel<C2><<<scat_grid, 256, 0, stream>>>(src, tgt, ety, deg, h1, Xr, r);
            k_gemm<C2, C3, true, false><<<g, 256, 0, stream>>>(
                Xr, W2all + (size_t)r * C2 * C3, nullptr, h2, N_NODES);
        }
    }
    k_colstats<C3><<<512, C3, 0, stream>>>(h2, sum2, ss2);
    k_bn<C3><<<cdivu((long long)N_NODES * C3, 256), 256, 0, stream>>>(h2, sum2, ss2, gamma2, beta2);

    // ---- final linear -> fp32 out ----
    {
        dim3 g(cdivu(N_NODES, 64), C3 / 64);
        k_gemm<C3, C3, false, true><<<g, 256, 0, stream>>>(h2, Wf, bf_, (float*)d_out, N_NODES);
    }
}

// Round 4
// 2967.076 us; speedup vs baseline: 1.4895x; 1.4895x over previous
//
#include <hip/hip_runtime.h>
#include <hip/hip_bf16.h>

// Problem constants (from reference)
#define N_NODES 50000
#define N_EDGES 800000
#define R 8
#define NB 30
#define C1 128
#define C2 256
#define C3 512
#define BN_EPS 1e-5f
#define ALPHA 0.01f

typedef __attribute__((ext_vector_type(8))) short short8;   // 8 bf16 = 4 VGPRs
typedef __attribute__((ext_vector_type(4))) float floatx4;  // MFMA C/D

static inline unsigned cdivu(long long a, long long b) { return (unsigned)((a + b - 1) / b); }

__device__ __forceinline__ short f2bs(float f) {
    __hip_bfloat16 h = __float2bfloat16(f);
    return *reinterpret_cast<short*>(&h);
}

// ---- basis combine + transpose: Wt[r][o][i] = sum_b comp[r,b]*basis[b][i][o], bf16 ----
template<int CIN, int COUT>
__global__ void k_wallt(const float* __restrict__ comp, const float* __restrict__ basis,
                        short* __restrict__ Wt) {
    int t = blockIdx.x * blockDim.x + threadIdx.x;
    if (t >= R * CIN * COUT) return;
    int r = t / (CIN * COUT);
    int io = t % (CIN * COUT);          // io = i*COUT + o (coalesced basis read)
    int i = io / COUT, o = io % COUT;
    float acc = 0.f;
    for (int b = 0; b < NB; ++b)
        acc += comp[r * NB + b] * basis[(size_t)b * CIN * COUT + io];
    Wt[(size_t)r * COUT * CIN + (size_t)o * CIN + i] = f2bs(acc);
}

// ---- transpose fp32 [CIN][COUT] -> bf16 [COUT][CIN] ----
template<int CIN, int COUT>
__global__ void k_tr(const float* __restrict__ Wm, short* __restrict__ Wt) {
    int t = blockIdx.x * blockDim.x + threadIdx.x;
    if (t >= CIN * COUT) return;
    int i = t / COUT, o = t % COUT;     // coalesced read
    Wt[(size_t)o * CIN + i] = f2bs(Wm[t]);
}

// ---- degree per (tgt, rel) ----
__global__ void k_deg(const int* __restrict__ tgt, const int* __restrict__ ety,
                      float* __restrict__ deg) {
    int e = blockIdx.x * blockDim.x + threadIdx.x;
    if (e >= N_EDGES) return;
    atomicAdd(&deg[tgt[e] * R + ety[e]], 1.0f);
}

__global__ void k_inv(float* __restrict__ deg) {
    int t = blockIdx.x * blockDim.x + threadIdx.x;
    if (t < N_NODES * R) deg[t] = 1.0f / fmaxf(deg[t], 1.0f);
}

// ---- per-relation scatter: Xr[tgt] += x[src] * inv[tgt*R+rel]  (wave per edge) ----
template<int CIN>
__global__ void k_scatter_rel(const int* __restrict__ src, const int* __restrict__ tgt,
                              const int* __restrict__ ety, const float* __restrict__ inv,
                              const float* __restrict__ x, float* __restrict__ Xr, int rel) {
    int e = blockIdx.x * 4 + (threadIdx.x >> 6);
    if (e >= N_EDGES) return;
    if (ety[e] != rel) return;          // wave-uniform exit
    int lane = threadIdx.x & 63;
    int s = src[e], t = tgt[e];
    float w = inv[t * R + rel];
    #pragma unroll
    for (int i = lane; i < CIN; i += 64)
        atomicAdd(&Xr[(size_t)t * CIN + i], x[(size_t)s * CIN + i] * w);
}

// ---- MFMA bf16 GEMM: C[M,CN] (+)= A_f32[M,K] @ Bt_bf16[CN,K]^T (+ bias) ----
// 128x128 block tile, BK=32, 4 waves of 64x64, mfma_f32_16x16x32_bf16.
// A staged fp32->bf16 into LDS (row stride 40 shorts, 16B aligned, <=2-way bank alias).
// B fragments loaded straight from global (transposed weights: 16B contiguous per lane).
template<int CN, bool ACC, bool BIAS>
__global__ __launch_bounds__(256) void k_mgemm(const float* __restrict__ A,
                                               const short* __restrict__ Bt,
                                               const float* __restrict__ bias,
                                               float* __restrict__ C, int M, int K) {
    __shared__ short As[128 * 40];
    const int tid = threadIdx.x;
    const int lane = tid & 63, wave = tid >> 6;
    const int wm = wave & 1, wn = wave >> 1;
    const int q = lane >> 4, ml = lane & 15;
    const int row0 = blockIdx.x * 128;
    const int col0 = blockIdx.y * 128;

    floatx4 acc[4][4] = {};

    for (int kt = 0; kt < K; kt += 32) {
        // stage A tile: 128 rows x 32 k, fp32 -> bf16, each thread 2 units of 8 floats
        #pragma unroll
        for (int c = 0; c < 2; ++c) {
            int u = tid + 256 * c;          // 0..511
            int row = u >> 2, k8 = (u & 3) * 8;
            short8 s;
            int grow = row0 + row;
            if (grow < M) {
                const float* p = &A[(size_t)grow * K + kt + k8];
                float4 a0 = *(const float4*)p;
                float4 a1 = *(const float4*)(p + 4);
                s[0] = f2bs(a0.x); s[1] = f2bs(a0.y); s[2] = f2bs(a0.z); s[3] = f2bs(a0.w);
                s[4] = f2bs(a1.x); s[5] = f2bs(a1.y); s[6] = f2bs(a1.z); s[7] = f2bs(a1.w);
            } else {
                s = (short8)0;
            }
            *(short8*)&As[row * 40 + k8] = s;
        }
        __syncthreads();

        // fragments + 16 MFMA
        short8 af[4], bfr[4];
        #pragma unroll
        for (int i = 0; i < 4; ++i) {
            int mrow = wm * 64 + i * 16 + ml;
            af[i] = *(const short8*)&As[mrow * 40 + q * 8];
        }
        #pragma unroll
        for (int j = 0; j < 4; ++j) {
            int col = col0 + wn * 64 + j * 16 + ml;
            bfr[j] = *(const short8*)&Bt[(size_t)col * K + kt + q * 8];
        }
        #pragma unroll
        for (int i = 0; i < 4; ++i)
            #pragma unroll
            for (int j = 0; j < 4; ++j)
                acc[i][j] = __builtin_amdgcn_mfma_f32_16x16x32_bf16(af[i], bfr[j], acc[i][j], 0, 0, 0);
        __syncthreads();
    }

    // epilogue: C/D layout col=lane&15, row=quad*4+reg
    #pragma unroll
    for (int i = 0; i < 4; ++i) {
        #pragma unroll
        for (int r = 0; r < 4; ++r) {
            int grow = row0 + wm * 64 + i * 16 + q * 4 + r;
            if (grow >= M) continue;
            #pragma unroll
            for (int j = 0; j < 4; ++j) {
                int gcol = col0 + wn * 64 + j * 16 + ml;
                float v = acc[i][j][r];
                if (BIAS) v += bias[gcol];
                size_t idx = (size_t)grow * CN + gcol;
                if (ACC) v += C[idx];
                C[idx] = v;
            }
        }
    }
}

// ---- per-column sum / sumsq ----
template<int C>
__global__ void k_colstats(const float* __restrict__ h, float* __restrict__ sum,
                           float* __restrict__ ss) {
    int c = threadIdx.x;
    float s = 0.f, q = 0.f;
    for (int r = blockIdx.x; r < N_NODES; r += gridDim.x) {
        float v = h[(size_t)r * C + c];
        s += v; q += v * v;
    }
    atomicAdd(&sum[c], s);
    atomicAdd(&ss[c], q);
}

// ---- BatchNorm (training stats, biased var) + LeakyReLU, in place ----
template<int C>
__global__ void k_bn(float* __restrict__ h, const float* __restrict__ sum,
                     const float* __restrict__ ss, const float* __restrict__ gamma,
                     const float* __restrict__ beta) {
    long long t = (long long)blockIdx.x * blockDim.x + threadIdx.x;
    if (t >= (long long)N_NODES * C) return;
    int c = (int)(t & (C - 1));
    const float invN = 1.0f / (float)N_NODES;
    float mu = sum[c] * invN;
    float var = ss[c] * invN - mu * mu;
    float y = (h[t] - mu) * rsqrtf(fmaxf(var, 0.f) + BN_EPS) * gamma[c] + beta[c];
    h[t] = y > 0.f ? y : ALPHA * y;
}

extern "C" void kernel_launch(void* const* d_in, const int* in_sizes, int n_in,
                              void* d_out, int out_size, void* d_ws, size_t ws_size,
                              hipStream_t stream) {
    const float* x      = (const float*)d_in[0];
    const int*   ei     = (const int*)d_in[1];
    const int*   ety    = (const int*)d_in[2];
    const float* basis1 = (const float*)d_in[3];
    const float* comp1  = (const float*)d_in[4];
    const float* root1  = (const float*)d_in[5];
    const float* bias1  = (const float*)d_in[6];
    const float* gamma1 = (const float*)d_in[7];
    const float* beta1  = (const float*)d_in[8];
    const float* basis2 = (const float*)d_in[9];
    const float* comp2  = (const float*)d_in[10];
    const float* root2  = (const float*)d_in[11];
    const float* bias2  = (const float*)d_in[12];
    const float* gamma2 = (const float*)d_in[13];
    const float* beta2  = (const float*)d_in[14];
    const float* Wf     = (const float*)d_in[15];
    const float* bf_    = (const float*)d_in[16];
    const int* src = ei;
    const int* tgt = ei + N_EDGES;

    // ---- workspace layout, ~211 MB ----
    float* ws = (float*)d_ws;
    float* h2    = ws;                                  // N*C3 f32
    float* h1    = h2    + (size_t)N_NODES * C3;        // N*C2 f32
    float* Xr    = h1    + (size_t)N_NODES * C2;        // N*C2 f32 (reused both layers)
    float* deg   = Xr    + (size_t)N_NODES * C2;        // N*R
    float* stats = deg   + (size_t)N_NODES * R;         // 1536
    short* W1t   = (short*)(stats + 1536);              // [R][C2][C1] bf16
    short* W2t   = W1t + (size_t)R * C2 * C1;           // [R][C3][C2] bf16
    short* r1t   = W2t + (size_t)R * C3 * C2;           // [C2][C1]
    short* r2t   = r1t + (size_t)C2 * C1;               // [C3][C2]
    short* Wft   = r2t + (size_t)C3 * C2;               // [C3][C3]
    float* sum1 = stats, *ss1 = stats + 256, *sum2 = stats + 512, *ss2 = stats + 1024;

    hipMemsetAsync(deg, 0, (size_t)N_NODES * R * 4, stream);
    hipMemsetAsync(stats, 0, 1536 * 4, stream);

    // weight prep (transposed bf16) + degrees
    k_wallt<C1, C2><<<cdivu((long long)R * C1 * C2, 256), 256, 0, stream>>>(comp1, basis1, W1t);
    k_wallt<C2, C3><<<cdivu((long long)R * C2 * C3, 256), 256, 0, stream>>>(comp2, basis2, W2t);
    k_tr<C1, C2><<<cdivu(C1 * C2, 256), 256, 0, stream>>>(root1, r1t);
    k_tr<C2, C3><<<cdivu(C2 * C3, 256), 256, 0, stream>>>(root2, r2t);
    k_tr<C3, C3><<<cdivu(C3 * C3, 256), 256, 0, stream>>>(Wf, Wft);
    k_deg<<<cdivu(N_EDGES, 256), 256, 0, stream>>>(tgt, ety, deg);
    k_inv<<<cdivu(N_NODES * R, 256), 256, 0, stream>>>(deg);

    const unsigned scat_grid = cdivu(N_EDGES, 4);   // wave per edge
    const unsigned mrows = cdivu(N_NODES, 128);     // 391

    // ---- layer 1: h1 = x@root1 + bias1 + sum_r Xr@W1[r] ----
    {
        dim3 g(mrows, C2 / 128);
        k_mgemm<C2, false, true><<<g, 256, 0, stream>>>(x, r1t, bias1, h1, N_NODES, C1);
        for (int r = 0; r < R; ++r) {
            hipMemsetAsync(Xr, 0, (size_t)N_NODES * C1 * 4, stream);
            k_scatter_rel<C1><<<scat_grid, 256, 0, stream>>>(src, tgt, ety, deg, x, Xr, r);
            k_mgemm<C2, true, false><<<g, 256, 0, stream>>>(
                Xr, W1t + (size_t)r * C2 * C1, nullptr, h1, N_NODES, C1);
        }
    }
    k_colstats<C2><<<512, C2, 0, stream>>>(h1, sum1, ss1);
    k_bn<C2><<<cdivu((long long)N_NODES * C2, 256), 256, 0, stream>>>(h1, sum1, ss1, gamma1, beta1);

    // ---- layer 2: h2 = h1@root2 + bias2 + sum_r Xr@W2[r] ----
    {
        dim3 g(mrows, C3 / 128);
        k_mgemm<C3, false, true><<<g, 256, 0, stream>>>(h1, r2t, bias2, h2, N_NODES, C2);
        for (int r = 0; r < R; ++r) {
            hipMemsetAsync(Xr, 0, (size_t)N_NODES * C2 * 4, stream);
            k_scatter_rel<C2><<<scat_grid, 256, 0, stream>>>(src, tgt, ety, deg, h1, Xr, r);
            k_mgemm<C3, true, false><<<g, 256, 0, stream>>>(
                Xr, W2t + (size_t)r * C3 * C2, nullptr, h2, N_NODES, C2);
        }
    }
    k_colstats<C3><<<512, C3, 0, stream>>>(h2, sum2, ss2);
    k_bn<C3><<<cdivu((long long)N_NODES * C3, 256), 256, 0, stream>>>(h2, sum2, ss2, gamma2, beta2);

    // ---- final linear -> fp32 out ----
    {
        dim3 g(mrows, C3 / 128);
        k_mgemm<C3, false, true><<<g, 256, 0, stream>>>(h2, Wft, bf_, (float*)d_out, N_NODES, C3);
    }
}

// Round 5
// 1217.951 us; speedup vs baseline: 3.6286x; 2.4361x over previous
//
#include <hip/hip_runtime.h>
#include <hip/hip_bf16.h>

#define N_NODES 50000
#define N_EDGES 800000
#define R 8
#define NB 30
#define C1 128
#define C2 256
#define C3 512
#define NR (N_NODES * R)
#define BN_EPS 1e-5f
#define ALPHA 0.01f
#define XSTRIDE 1024          // regionA row stride (bf16 elems), both layers

typedef unsigned short u16;
typedef __attribute__((ext_vector_type(8))) short short8;
typedef __attribute__((ext_vector_type(4))) float floatx4;

static inline unsigned cdivu(long long a, long long b) { return (unsigned)((a + b - 1) / b); }

__device__ __forceinline__ u16 f2bs(float f) {
    __hip_bfloat16 h = __float2bfloat16(f);
    return *reinterpret_cast<u16*>(&h);
}
__device__ __forceinline__ float b2f(u16 u) {
    return __uint_as_float(((unsigned)u) << 16);
}
__device__ __forceinline__ float ldacc(const float* p) { return *p; }
__device__ __forceinline__ float ldacc(const u16* p) { return b2f(*p); }
__device__ __forceinline__ void stv(float* p, float v) { *p = v; }
__device__ __forceinline__ void stv(u16* p, float v) { *p = f2bs(v); }

// ---- weight builders: Bt[o][k] bf16, k = [rel-blocks | root] ----
__global__ void k_b1(const float* __restrict__ comp, const float* __restrict__ basis,
                     const float* __restrict__ root, u16* __restrict__ Bt) {
    int t = blockIdx.x * blockDim.x + threadIdx.x;
    if (t >= C2 * 1152) return;
    int o = t % C2, k = t / C2;         // coalesced basis/root reads over o
    float v;
    if (k < R * C1) {
        int r = k >> 7, i = k & 127;
        v = 0.f;
        for (int b = 0; b < NB; ++b)
            v += comp[r * NB + b] * basis[((size_t)b * C1 + i) * C2 + o];
    } else v = root[(size_t)(k - R * C1) * C2 + o];
    Bt[(size_t)o * 1152 + k] = f2bs(v);
}
__global__ void k_b2(const float* __restrict__ comp, const float* __restrict__ basis,
                     const float* __restrict__ root, u16* __restrict__ Bt) {
    int t = blockIdx.x * blockDim.x + threadIdx.x;
    if (t >= C3 * 2304) return;
    int o = t % C3, k = t / C3;
    float v;
    if (k < R * C2) {
        int r = k >> 8, i = k & 255;
        v = 0.f;
        for (int b = 0; b < NB; ++b)
            v += comp[r * NB + b] * basis[((size_t)b * C2 + i) * C3 + o];
    } else v = root[(size_t)(k - R * C2) * C3 + o];
    Bt[(size_t)o * 2304 + k] = f2bs(v);
}
__global__ void k_btf(const float* __restrict__ Wf, u16* __restrict__ Bt) {
    int t = blockIdx.x * blockDim.x + threadIdx.x;
    if (t >= C3 * C3) return;
    int o = t % C3, k = t / C3;
    Bt[(size_t)o * C3 + k] = f2bs(Wf[(size_t)k * C3 + o]);
}

// ---- x fp32 -> bf16 ----
__global__ void k_f2b(const float* __restrict__ s, u16* __restrict__ d, long long n) {
    long long t = (long long)blockIdx.x * blockDim.x + threadIdx.x;
    if (t < n) d[t] = f2bs(s[t]);
}

// ---- CSR build ----
__global__ void k_count(const int* __restrict__ tgt, const int* __restrict__ ety,
                        int* __restrict__ cnt) {
    int e = blockIdx.x * blockDim.x + threadIdx.x;
    if (e >= N_EDGES) return;
    atomicAdd(&cnt[tgt[e] * R + ety[e]], 1);
}
__global__ void k_scan1(const int* __restrict__ cnt, int* __restrict__ off,
                        int* __restrict__ bsum) {
    __shared__ int s[256];
    int tid = threadIdx.x;
    int i = blockIdx.x * 256 + tid;
    int v = (i < NR) ? cnt[i] : 0;
    s[tid] = v;
    __syncthreads();
    for (int o = 1; o < 256; o <<= 1) {
        int x = (tid >= o) ? s[tid - o] : 0;
        __syncthreads();
        s[tid] += x;
        __syncthreads();
    }
    if (i < NR) off[i] = s[tid] - v;            // exclusive within block
    if (tid == 255) bsum[blockIdx.x] = s[255];
}
__global__ void k_scan2(int* __restrict__ bsum, int nb) {
    __shared__ int s[256];
    __shared__ int carry_s;
    int tid = threadIdx.x;
    if (tid == 0) carry_s = 0;
    __syncthreads();
    for (int base = 0; base < nb; base += 256) {
        int i = base + tid;
        int v = (i < nb) ? bsum[i] : 0;
        s[tid] = v;
        __syncthreads();
        for (int o = 1; o < 256; o <<= 1) {
            int x = (tid >= o) ? s[tid - o] : 0;
            __syncthreads();
            s[tid] += x;
            __syncthreads();
        }
        int carry = carry_s;
        if (i < nb) bsum[i] = s[tid] - v + carry;
        int tot = s[255];
        __syncthreads();
        if (tid == 0) carry_s = carry + tot;
        __syncthreads();
    }
}
__global__ void k_scan3(int* __restrict__ off, const int* __restrict__ bsum,
                        int* __restrict__ cursor) {
    int i = blockIdx.x * 256 + threadIdx.x;
    if (i < NR) {
        int v = off[i] + bsum[blockIdx.x];
        off[i] = v;
        cursor[i] = v;
    }
    if (i == 0) off[NR] = N_EDGES;
}
__global__ void k_fill(const int* __restrict__ src, const int* __restrict__ tgt,
                       const int* __restrict__ ety, int* __restrict__ cursor,
                       int* __restrict__ esrc) {
    int e = blockIdx.x * blockDim.x + threadIdx.x;
    if (e >= N_EDGES) return;
    int pos = atomicAdd(&cursor[tgt[e] * R + ety[e]], 1);
    esrc[pos] = src[e];
}

// ---- gather: mean of src rows per (tgt, rel), bf16 in/out, no atomics ----
// wave per (t, rr); writes regionA[t][rr*CIN .. +CIN), row stride XSTRIDE.
template<int CIN, int NREL>
__global__ void k_gather(const int* __restrict__ off, const int* __restrict__ esrc,
                         const u16* __restrict__ srcbf, u16* __restrict__ Xbar, int r0) {
    int wid = blockIdx.x * 4 + (threadIdx.x >> 6);
    if (wid >= N_NODES * NREL) return;
    int lane = threadIdx.x & 63;
    int t = wid / NREL, rr = wid - t * NREL;
    int b = t * R + r0 + rr;
    int o0 = off[b], o1 = off[b + 1];
    constexpr int PER = CIN / 64;       // 2 or 4
    float acc[PER] = {};
    for (int j = o0; j < o1; ++j) {
        int s = esrc[j];
        const u16* p = &srcbf[(size_t)s * CIN + lane * PER];
        if (PER == 4) {
            ushort4 v = *(const ushort4*)p;
            acc[0] += b2f(v.x); acc[1] += b2f(v.y); acc[2] += b2f(v.z); acc[3] += b2f(v.w);
        } else {
            ushort2 v = *(const ushort2*)p;
            acc[0] += b2f(v.x); acc[1] += b2f(v.y);
        }
    }
    float w = (o1 > o0) ? 1.f / (float)(o1 - o0) : 0.f;
    u16* q = &Xbar[(size_t)t * XSTRIDE + rr * CIN + lane * PER];
    if (PER == 4) {
        ushort4 v;
        v.x = f2bs(acc[0] * w); v.y = f2bs(acc[1] * w);
        v.z = f2bs(acc[2] * w); v.w = f2bs(acc[3] * w);
        *(ushort4*)q = v;
    } else {
        ushort2 v;
        v.x = f2bs(acc[0] * w); v.y = f2bs(acc[1] * w);
        *(ushort2*)q = v;
    }
}

// ---- MFMA bf16 GEMM: C[M,CN] (+)= [A0|A1](bf16) @ Bt^T (+ bias) ----
// 128x128 tile, BK=32, 4 waves of 64x64. A row source switches at Ksplit.
template<int CN, typename OT, bool ACC, bool BIAS>
__global__ __launch_bounds__(256) void k_mgemm(
        const u16* __restrict__ A0, int sA0, int Ksplit,
        const u16* __restrict__ A1, int sA1, int Ktot,
        const u16* __restrict__ Bt, int sB,
        const float* __restrict__ bias, OT* __restrict__ C, int M) {
    __shared__ u16 As[128 * 40];
    const int tid = threadIdx.x;
    const int lane = tid & 63, wave = tid >> 6;
    const int wm = wave & 1, wn = wave >> 1;
    const int q = lane >> 4, ml = lane & 15;
    const int col0 = blockIdx.x * 128;      // x = col: consecutive blocks share A rows
    const int row0 = blockIdx.y * 128;

    floatx4 acc[4][4] = {};
    for (int kt = 0; kt < Ktot; kt += 32) {
        const bool first = (kt < Ksplit);
        const u16* Ab = first ? A0 : A1;
        const int sA = first ? sA0 : sA1;
        const int kl = first ? kt : kt - Ksplit;
        #pragma unroll
        for (int c = 0; c < 2; ++c) {
            int u = tid + 256 * c;          // 0..511
            int row = u >> 2, k8 = (u & 3) * 8;
            int grow = row0 + row; grow = grow < M ? grow : M - 1;
            short8 v = *(const short8*)(Ab + (size_t)grow * sA + kl + k8);
            *(short8*)&As[row * 40 + k8] = v;
        }
        __syncthreads();
        short8 af[4], bfr[4];
        #pragma unroll
        for (int i = 0; i < 4; ++i)
            af[i] = *(const short8*)&As[(wm * 64 + i * 16 + ml) * 40 + q * 8];
        #pragma unroll
        for (int j = 0; j < 4; ++j) {
            int col = col0 + wn * 64 + j * 16 + ml;
            bfr[j] = *(const short8*)(Bt + (size_t)col * sB + kt + q * 8);
        }
        #pragma unroll
        for (int i = 0; i < 4; ++i)
            #pragma unroll
            for (int j = 0; j < 4; ++j)
                acc[i][j] = __builtin_amdgcn_mfma_f32_16x16x32_bf16(af[i], bfr[j], acc[i][j], 0, 0, 0);
        __syncthreads();
    }
    #pragma unroll
    for (int i = 0; i < 4; ++i) {
        #pragma unroll
        for (int rr = 0; rr < 4; ++rr) {
            int grow = row0 + wm * 64 + i * 16 + q * 4 + rr;
            if (grow >= M) continue;
            #pragma unroll
            for (int j = 0; j < 4; ++j) {
                int gcol = col0 + wn * 64 + j * 16 + ml;
                float v = acc[i][j][rr];
                if (BIAS) v += bias[gcol];
                size_t idx = (size_t)grow * CN + gcol;
                if (ACC) v += ldacc(&C[idx]);
                stv(&C[idx], v);
            }
        }
    }
}

// ---- per-column stats on bf16 ----
template<int C>
__global__ void k_colstats_bf(const u16* __restrict__ h, float* __restrict__ sum,
                              float* __restrict__ ss) {
    int c = threadIdx.x;
    float s = 0.f, q = 0.f;
    for (int r = blockIdx.x; r < N_NODES; r += gridDim.x) {
        float v = b2f(h[(size_t)r * C + c]);
        s += v; q += v * v;
    }
    atomicAdd(&sum[c], s);
    atomicAdd(&ss[c], q);
}

// ---- BatchNorm + LeakyReLU, bf16 in place ----
template<int C>
__global__ void k_bn_bf(u16* __restrict__ h, const float* __restrict__ sum,
                        const float* __restrict__ ss, const float* __restrict__ gamma,
                        const float* __restrict__ beta) {
    long long t = (long long)blockIdx.x * blockDim.x + threadIdx.x;
    if (t >= (long long)N_NODES * C) return;
    int c = (int)(t & (C - 1));
    const float invN = 1.0f / (float)N_NODES;
    float mu = sum[c] * invN;
    float var = ss[c] * invN - mu * mu;
    float y = (b2f(h[t]) - mu) * rsqrtf(fmaxf(var, 0.f) + BN_EPS) * gamma[c] + beta[c];
    h[t] = f2bs(y > 0.f ? y : ALPHA * y);
}

extern "C" void kernel_launch(void* const* d_in, const int* in_sizes, int n_in,
                              void* d_out, int out_size, void* d_ws, size_t ws_size,
                              hipStream_t stream) {
    const float* x      = (const float*)d_in[0];
    const int*   ei     = (const int*)d_in[1];
    const int*   ety    = (const int*)d_in[2];
    const float* basis1 = (const float*)d_in[3];
    const float* comp1  = (const float*)d_in[4];
    const float* root1  = (const float*)d_in[5];
    const float* bias1  = (const float*)d_in[6];
    const float* gamma1 = (const float*)d_in[7];
    const float* beta1  = (const float*)d_in[8];
    const float* basis2 = (const float*)d_in[9];
    const float* comp2  = (const float*)d_in[10];
    const float* root2  = (const float*)d_in[11];
    const float* bias2  = (const float*)d_in[12];
    const float* gamma2 = (const float*)d_in[13];
    const float* beta2  = (const float*)d_in[14];
    const float* Wf     = (const float*)d_in[15];
    const float* bf_    = (const float*)d_in[16];
    const int* src = ei;
    const int* tgt = ei + N_EDGES;

    // ---- workspace layout (~203 MB) ----
    const int nscanb = (NR + 255) / 256;    // 1563
    char* p = (char*)d_ws;
    auto alloc = [&](size_t bytes) { void* r = (void*)p; p += (bytes + 63) & ~63ULL; return r; };
    u16* regionA = (u16*)alloc((size_t)N_NODES * XSTRIDE * 2);  // 102.4 MB
    u16* h1bf    = (u16*)alloc((size_t)N_NODES * C2 * 2);       // 25.6 MB
    u16* h2bf    = (u16*)alloc((size_t)N_NODES * C3 * 2);       // 51.2 MB
    u16* xbf     = (u16*)alloc((size_t)N_NODES * C1 * 2);       // 12.8 MB
    int* cnt     = (int*)alloc((size_t)NR * 4);
    int* off     = (int*)alloc((size_t)(NR + 1) * 4);
    int* cursor  = (int*)alloc((size_t)NR * 4);
    int* esrc    = (int*)alloc((size_t)N_EDGES * 4);
    int* bsum    = (int*)alloc((size_t)nscanb * 4);
    u16* Bt1     = (u16*)alloc((size_t)C2 * 1152 * 2);
    u16* Bt2     = (u16*)alloc((size_t)C3 * 2304 * 2);
    u16* Btf     = (u16*)alloc((size_t)C3 * C3 * 2);
    float* stats = (float*)alloc(1536 * 4);
    float* sum1 = stats, *ss1 = stats + 256, *sum2 = stats + 512, *ss2 = stats + 1024;

    hipMemsetAsync(cnt, 0, (size_t)NR * 4, stream);
    hipMemsetAsync(stats, 0, 1536 * 4, stream);

    // weights + x->bf16 + CSR
    k_b1<<<cdivu((long long)C2 * 1152, 256), 256, 0, stream>>>(comp1, basis1, root1, Bt1);
    k_b2<<<cdivu((long long)C3 * 2304, 256), 256, 0, stream>>>(comp2, basis2, root2, Bt2);
    k_btf<<<cdivu((long long)C3 * C3, 256), 256, 0, stream>>>(Wf, Btf);
    k_f2b<<<cdivu((long long)N_NODES * C1, 256), 256, 0, stream>>>(x, xbf, (long long)N_NODES * C1);
    k_count<<<cdivu(N_EDGES, 256), 256, 0, stream>>>(tgt, ety, cnt);
    k_scan1<<<nscanb, 256, 0, stream>>>(cnt, off, bsum);
    k_scan2<<<1, 256, 0, stream>>>(bsum, nscanb);
    k_scan3<<<nscanb, 256, 0, stream>>>(off, bsum, cursor);
    k_fill<<<cdivu(N_EDGES, 256), 256, 0, stream>>>(src, tgt, ety, cursor, esrc);

    // ---- layer 1: A = [mean_r(x) x8 | x], K=1152 -> h1bf ----
    k_gather<C1, 8><<<cdivu((long long)N_NODES * 8, 4), 256, 0, stream>>>(off, esrc, xbf, regionA, 0);
    {
        dim3 g(C2 / 128, cdivu(N_NODES, 128));
        k_mgemm<C2, u16, false, true><<<g, 256, 0, stream>>>(
            regionA, XSTRIDE, 1024, xbf, C1, 1152, Bt1, 1152, bias1, h1bf, N_NODES);
    }
    k_colstats_bf<C2><<<512, C2, 0, stream>>>(h1bf, sum1, ss1);
    k_bn_bf<C2><<<cdivu((long long)N_NODES * C2, 256), 256, 0, stream>>>(h1bf, sum1, ss1, gamma1, beta1);

    // ---- layer 2 (two K-halves): h2 = [mean r0..3]@W + bias, += [mean r4..7 | h1]@W ----
    {
        dim3 g(C3 / 128, cdivu(N_NODES, 128));
        k_gather<C2, 4><<<cdivu((long long)N_NODES * 4, 4), 256, 0, stream>>>(off, esrc, h1bf, regionA, 0);
        k_mgemm<C3, u16, false, true><<<g, 256, 0, stream>>>(
            regionA, XSTRIDE, 1024, (const u16*)nullptr, 0, 1024, Bt2, 2304, bias2, h2bf, N_NODES);
        k_gather<C2, 4><<<cdivu((long long)N_NODES * 4, 4), 256, 0, stream>>>(off, esrc, h1bf, regionA, 4);
        k_mgemm<C3, u16, true, false><<<g, 256, 0, stream>>>(
            regionA, XSTRIDE, 1024, h1bf, C2, 1280, Bt2 + 1024, 2304, nullptr, h2bf, N_NODES);
    }
    k_colstats_bf<C3><<<512, C3, 0, stream>>>(h2bf, sum2, ss2);
    k_bn_bf<C3><<<cdivu((long long)N_NODES * C3, 256), 256, 0, stream>>>(h2bf, sum2, ss2, gamma2, beta2);

    // ---- final linear -> fp32 out ----
    {
        dim3 g(C3 / 128, cdivu(N_NODES, 128));
        k_mgemm<C3, float, false, true><<<g, 256, 0, stream>>>(
            h2bf, C3, 512, (const u16*)nullptr, 0, 512, Btf, C3, bf_, (float*)d_out, N_NODES);
    }
}